// Round 4
// baseline (479.127 us; speedup 1.0000x reference)
//
#include <hip/hip_runtime.h>

#define B 32
#define D 1024
#define UD 256
#define ENT 32
#define NENT 64
#define S 2048
#define C 65
#define NSLAB 16
#define SROWS (S / NSLAB)   // 128

__device__ __forceinline__ float dot4(float4 w, const float* q) {
    return w.x * q[0] + w.y * q[1] + w.z * q[2] + w.w * q[3];
}

__device__ __forceinline__ float wave_sum(float v) {
#pragma unroll
    for (int o = 32; o >= 1; o >>= 1) v += __shfl_xor(v, o);
    return v;
}

// grid (40, 8): x = 32-row group of [W_unit; W_chunk] (1280 rows), y = 4-batch group.
// Linear id = x + 40*y -> all 8 same-slice blocks land on XCD x%8 (40%8==0): W fetched
// from HBM once (5.2 MB), served from L2 thereafter. Wave-per-row: 64 lanes * float4
// = 1 KB contiguous per load instruction.
__global__ __launch_bounds__(256) void k_proj(const float* __restrict__ src,
                                              const float* __restrict__ Wu,
                                              const float* __restrict__ Wc,
                                              float* __restrict__ qu,
                                              float* __restrict__ qc) {
    __shared__ alignas(16) float s_src[4][D];       // 16 KB
    int t = threadIdx.x, rg = blockIdx.x, bg = blockIdx.y;
    for (int f = t; f < 4 * (D / 4); f += 256) {
        int bb = f >> 8, i4 = f & 255;
        *(float4*)(&s_src[bb][i4 * 4]) =
            *(const float4*)(src + (size_t)(bg * 4 + bb) * D + i4 * 4);
    }
    __syncthreads();
    int w = t >> 6, l = t & 63;
#pragma unroll
    for (int pass = 0; pass < 8; ++pass) {
        int r = pass * 4 + w;
        int gj = rg * 32 + r;
        const float4* wrow = (const float4*)((gj < UD) ? (Wu + (size_t)gj * D)
                                                       : (Wc + (size_t)(gj - UD) * D));
        float acc[4] = {0.f, 0.f, 0.f, 0.f};
#pragma unroll
        for (int p = 0; p < 4; ++p) {
            float4 wv = wrow[p * 64 + l];
            int k = p * 256 + l * 4;
#pragma unroll
            for (int bb = 0; bb < 4; ++bb) acc[bb] += dot4(wv, &s_src[bb][k]);
        }
#pragma unroll
        for (int bb = 0; bb < 4; ++bb) acc[bb] = wave_sum(acc[bb]);
        if (l == 0) {
#pragma unroll
            for (int bb = 0; bb < 4; ++bb) {
                int b = bg * 4 + bb;
                if (gj < UD) qu[b * UD + gj] = acc[bb];
                else qc[b * D + (gj - UD)] = acc[bb];
            }
        }
    }
}

// grid (NENT+1, B): x<NENT -> unit scores + per-entity masked softmax (wave-per-row,
// fully coalesced: 64 lanes * float4 = one 256-float pe row per instruction).
// x==NENT -> chunk scores + masked softmax (drop chunk 0).
__global__ __launch_bounds__(256) void k_scores(const float* __restrict__ pe,
                                                const float* __restrict__ hl,
                                                const int* __restrict__ lmask,
                                                const int* __restrict__ hmask,
                                                const float* __restrict__ qu,
                                                const float* __restrict__ qc,
                                                float* __restrict__ out_au,
                                                float* __restrict__ out_ac) {
    __shared__ alignas(16) float q[D];
    __shared__ float sc[C];
    __shared__ float red2[2];
    int x = blockIdx.x, b = blockIdx.y, t = threadIdx.x;
    if (x < NENT) {
        int n = x;
        if (t < UD) q[t] = qu[b * UD + t];
        __syncthreads();
        int w = t >> 6, l = t & 63;
#pragma unroll
        for (int pass = 0; pass < 8; ++pass) {
            int e = pass * 4 + w;
            const float4* row = (const float4*)pe + (size_t)((n * ENT + e) * B + b) * (UD / 4);
            float acc = wave_sum(dot4(row[l], &q[l * 4]));
            if (l == 0) sc[e] = acc;
        }
        __syncthreads();
        if (t < ENT) {
            bool m = lmask[(size_t)n * B * ENT + b * ENT + t] != 0;
            float v = m ? -1e30f : sc[t];
            float mx = v;
#pragma unroll
            for (int o = 16; o >= 1; o >>= 1) mx = fmaxf(mx, __shfl_xor(mx, o));
            float p = m ? 0.f : __expf(v - mx);
            float sm = p;
#pragma unroll
            for (int o = 16; o >= 1; o >>= 1) sm += __shfl_xor(sm, o);
            out_au[b * S + n * ENT + t] = (sm > 0.f) ? (p / sm) : 0.f;
        }
    } else {
        for (int i = t; i < D / 4; i += 256)
            *(float4*)(&q[i * 4]) = *(const float4*)(qc + (size_t)b * D + i * 4);
        __syncthreads();
        int w = t >> 6, l = t & 63;
        for (int c = w; c < C; c += 4) {
            const float4* hp = (const float4*)(hl + (size_t)(c * B + b) * D);
            float acc = 0.f;
#pragma unroll
            for (int i = 0; i < 4; ++i) {
                int f = l + 64 * i;
                acc += dot4(hp[f], &q[f * 4]);
            }
            acc = wave_sum(acc);
            if (l == 0) sc[c] = acc;
        }
        __syncthreads();
        if (t == 0) {
            float mx = -1e30f;
            for (int c = 0; c < C; ++c) {
                float v = hmask[b * C + c] ? -1e30f : sc[c];
                mx = fmaxf(mx, v);
            }
            float sm = 0.f;
            for (int c = 0; c < C; ++c) {
                float v = hmask[b * C + c] ? -1e30f : sc[c];
                sm += __expf(v - mx);
            }
            red2[0] = mx;
            red2[1] = sm;
        }
        __syncthreads();
        if (t >= 1 && t < C) {
            bool m = hmask[b * C + t] != 0;
            float p = m ? 0.f : __expf(sc[t] - red2[0]) / red2[1];
            out_ac[b * NENT + (t - 1)] = p;
        }
    }
}

// grid (NSLAB, B): block owns one 128-row s-slab of one batch, full D width.
// 512 blocks = 2 blocks/CU. Writes slab partials pf (no atomics) + out_av.
__global__ __launch_bounds__(256) void k_ctx(const float* __restrict__ ll,
                                             const float* __restrict__ out_au,
                                             const float* __restrict__ out_ac,
                                             float* __restrict__ pf,
                                             float* __restrict__ out_av) {
    __shared__ float s_av[SROWS];
    int ss = blockIdx.x, b = blockIdx.y, t = threadIdx.x;
    if (t < SROWS) {
        int s = ss * SROWS + t;
        int n = s >> 5;  // ENT=32
        float a = out_ac[b * NENT + n] * out_au[b * S + s];
        s_av[t] = a;
        out_av[b * S + s] = a;
    }
    __syncthreads();
    float4 acc = {0.f, 0.f, 0.f, 0.f};
    const float4* base = (const float4*)ll + ((size_t)(ss * SROWS) * B + b) * (D / 4) + t;
#pragma unroll 8
    for (int j = 0; j < SROWS; ++j) {
        float4 x = base[(size_t)j * (B * D / 4)];
        float wv = s_av[j];
        acc.x += wv * x.x;
        acc.y += wv * x.y;
        acc.z += wv * x.z;
        acc.w += wv * x.w;
    }
    *(float4*)(pf + (size_t)(ss * B + b) * D + t * 4) = acc;
}

// grid (B*D/256): cf = sum over NSLAB slab partials (2 MB read)
__global__ __launch_bounds__(256) void k_red(const float* __restrict__ pf,
                                             float* __restrict__ cf) {
    int f = blockIdx.x * 256 + threadIdx.x;
    float s = 0.f;
#pragma unroll
    for (int ss = 0; ss < NSLAB; ++ss) s += pf[(size_t)ss * B * D + f];
    cf[f] = s;
}

// grid (16, 8): x = 64-row group of W_out, y = 4-batch group.
// Linear id = x + 16*y -> all 8 same-slice blocks on XCD x%8 (Wo slice L2-resident).
// Wave-per-row: 64 lanes * float4 = 1 KB contiguous per load instruction.
__global__ __launch_bounds__(256) void k_out(const float* __restrict__ Wo,
                                             const float* __restrict__ src,
                                             const float* __restrict__ cf,
                                             float* __restrict__ out_h) {
    __shared__ alignas(16) float cc[4][2 * D];      // 32 KB concat for 4 batches
    int t = threadIdx.x, jg = blockIdx.x, bg = blockIdx.y;
    for (int f = t; f < 4 * (2 * D / 4); f += 256) {  // 2048 float4s
        int bb = f >> 9, part = f & 511;
        int b = bg * 4 + bb;
        float4 v;
        if (part < 256) v = *(const float4*)(cf + (size_t)b * D + part * 4);
        else v = *(const float4*)(src + (size_t)b * D + (part - 256) * 4);
        *(float4*)(&cc[bb][part * 4]) = v;
    }
    __syncthreads();
    int w = t >> 6, l = t & 63;
#pragma unroll
    for (int pass = 0; pass < 16; ++pass) {
        int r = pass * 4 + w;
        int j = jg * 64 + r;
        const float4* wrow = (const float4*)(Wo + (size_t)j * 2 * D);
        float acc[4] = {0.f, 0.f, 0.f, 0.f};
#pragma unroll
        for (int p = 0; p < 8; ++p) {
            float4 wv = wrow[p * 64 + l];
            int k = p * 256 + l * 4;
#pragma unroll
            for (int bb = 0; bb < 4; ++bb) acc[bb] += dot4(wv, &cc[bb][k]);
        }
#pragma unroll
        for (int bb = 0; bb < 4; ++bb) acc[bb] = wave_sum(acc[bb]);
        if (l == 0) {
#pragma unroll
            for (int bb = 0; bb < 4; ++bb)
                out_h[(size_t)(bg * 4 + bb) * D + j] = tanhf(acc[bb]);
        }
    }
}

extern "C" void kernel_launch(void* const* d_in, const int* in_sizes, int n_in,
                              void* d_out, int out_size, void* d_ws, size_t ws_size,
                              hipStream_t stream) {
    const float* src = (const float*)d_in[0];
    const float* hl = (const float*)d_in[1];
    const float* pe = (const float*)d_in[2];
    const float* ll = (const float*)d_in[3];
    const int* lmask = (const int*)d_in[4];
    const int* hmask = (const int*)d_in[5];
    const float* Wu = (const float*)d_in[6];
    const float* Wc = (const float*)d_in[7];
    const float* Wo = (const float*)d_in[8];

    float* out = (float*)d_out;
    float* out_h = out;                      // (B, D)
    float* out_av = out + B * D;             // (B, S)
    float* out_ac = out_av + B * S;          // (B, NENT)
    float* out_au = out_ac + B * NENT;       // (B, S)

    float* ws = (float*)d_ws;
    float* qu = ws;                          // B*UD
    float* qc = qu + B * UD;                 // B*D
    float* cf = qc + B * D;                  // B*D
    float* pf = cf + B * D;                  // NSLAB*B*D slab partials (2 MB)

    k_proj<<<dim3(40, 8), 256, 0, stream>>>(src, Wu, Wc, qu, qc);
    k_scores<<<dim3(NENT + 1, B), 256, 0, stream>>>(pe, hl, lmask, hmask, qu, qc,
                                                    out_au, out_ac);
    k_ctx<<<dim3(NSLAB, B), 256, 0, stream>>>(ll, out_au, out_ac, pf, out_av);
    k_red<<<dim3(B * D / 256), 256, 0, stream>>>(pf, cf);
    k_out<<<dim3(16, 8), 256, 0, stream>>>(Wo, src, cf, out_h);
}